// Round 3
// baseline (131.026 us; speedup 1.0000x reference)
//
#include <hip/hip_runtime.h>
#include <math.h>

#define EMBED 768
#define SEQ   2048
#define NB    8
#define SQRT_E 27.712812921102035f   // sqrt(768), folded into Wq at split time

typedef short  short8 __attribute__((ext_vector_type(8)));
typedef float  f32x4  __attribute__((ext_vector_type(4)));

// ws layout (ushort element offsets)
#define WHI_OFF  0u
#define WLO_OFF  147456u
#define QHI_OFF  294912u
#define QLO_OFF  (294912u + 1u*1048576u)
#define KHI_OFF  (294912u + 2u*1048576u)
#define KLO_OFF  (294912u + 3u*1048576u)
#define VT_OFF   (294912u + 4u*1048576u)

__device__ __forceinline__ ushort f2bf(float f) {          // round-to-nearest
    unsigned u = __float_as_uint(f);
    return (ushort)((u + 0x7FFFu + ((u >> 16) & 1u)) >> 16);
}
__device__ __forceinline__ ushort f2bf_trunc(float f) {    // cheap, for lo part
    return (ushort)(__float_as_uint(f) >> 16);
}
__device__ __forceinline__ float bf2f(ushort h) {
    return __uint_as_float(((unsigned)h) << 16);
}

// ---------------------------------------------------------------------------
// Kernel 0: split W into bf16 hi/lo.  rows: [0,64)=Wq*sqrt(E), [64,128)=Wk,
// [128,192)=Wv.  w_hi/w_lo are [192][768] bf16 row-major.
// ---------------------------------------------------------------------------
__global__ __launch_bounds__(256)
void split_w_kernel(const float* __restrict__ Wq, const float* __restrict__ Wk,
                    const float* __restrict__ Wv,
                    ushort* __restrict__ w_hi, ushort* __restrict__ w_lo)
{
    int idx = blockIdx.x * 256 + threadIdx.x;
    if (idx >= 192 * EMBED) return;
    int row = idx / EMBED, e = idx - row * EMBED;
    float f;
    if (row < 64)       f = Wq[row * EMBED + e] * SQRT_E;
    else if (row < 128) f = Wk[(row - 64) * EMBED + e];
    else                f = Wv[(row - 128) * EMBED + e];
    ushort hi = f2bf(f);
    w_hi[idx] = hi;
    w_lo[idx] = f2bf_trunc(f - bf2f(hi));
}

// ---------------------------------------------------------------------------
// Kernel 1: QKV projection, barrier-free / LDS-free.
// Wave = 16 rows x 96 cols (6 interleaved n-tiles: ntg = 2*j + ch).
// Block = 256 thr = 4 waves = [2 row-tiles] x [2 col-halves]; the two
// col-halves of the same rows share x via L1/L2.  Grid 512 blocks.
// x converted fp32 -> bf16 hi/lo in registers; W hi/lo read from L2.
// q,k columns use 3-product split; v single product.
// ---------------------------------------------------------------------------
__global__ __launch_bounds__(256)
void proj_kernel(const float* __restrict__ x,
                 const ushort* __restrict__ w_hi, const ushort* __restrict__ w_lo,
                 ushort* __restrict__ q_hi, ushort* __restrict__ q_lo,
                 ushort* __restrict__ k_hi, ushort* __restrict__ k_lo,
                 ushort* __restrict__ v_t)
{
    const int t    = threadIdx.x;
    const int lane = t & 63;
    const int wid  = t >> 6;
    const int wr   = wid >> 1;     // row-tile within block
    const int ch   = wid & 1;      // col half (even/odd n-tiles)
    const int ln   = lane & 15;
    const int kg   = lane >> 4;
    const int rt   = blockIdx.x * 2 + wr;   // 0..1023
    const int row0 = rt * 16;

    const float* xp = x + (size_t)(row0 + ln) * EMBED + kg * 8;

    const ushort* wph[6];
    const ushort* wpl[6];
#pragma unroll
    for (int j = 0; j < 6; ++j) {
        int ntg = 2 * j + ch;
        wph[j] = w_hi + (size_t)(ntg * 16 + ln) * EMBED + kg * 8;
        wpl[j] = w_lo + (size_t)(ntg * 16 + ln) * EMBED + kg * 8;
    }

    const f32x4 vzero = {0.f, 0.f, 0.f, 0.f};
    f32x4 acc[6];
#pragma unroll
    for (int j = 0; j < 6; ++j) acc[j] = vzero;

    for (int e0 = 0; e0 < EMBED; e0 += 32) {
        float4 f0 = *(const float4*)(xp + e0);
        float4 f1 = *(const float4*)(xp + e0 + 4);
        const float fv[8] = {f0.x, f0.y, f0.z, f0.w, f1.x, f1.y, f1.z, f1.w};
        short8 ah, al;
#pragma unroll
        for (int i = 0; i < 8; ++i) {
            ushort h = f2bf(fv[i]);
            ah[i] = (short)h;
            al[i] = (short)f2bf_trunc(fv[i] - bf2f(h));
        }
#pragma unroll
        for (int j = 0; j < 6; ++j) {
            const int ntg = 2 * j + ch;
            short8 bh = *(const short8*)(wph[j] + e0);
            acc[j] = __builtin_amdgcn_mfma_f32_16x16x32_bf16(ah, bh, acc[j], 0, 0, 0);
            if (ntg < 8) {
                short8 bl = *(const short8*)(wpl[j] + e0);
                acc[j] = __builtin_amdgcn_mfma_f32_16x16x32_bf16(ah, bl, acc[j], 0, 0, 0);
                acc[j] = __builtin_amdgcn_mfma_f32_16x16x32_bf16(al, bh, acc[j], 0, 0, 0);
            }
        }
    }

    // epilogue: C layout col=lane&15, row=(lane>>4)*4+reg
#pragma unroll
    for (int j = 0; j < 6; ++j) {
        const int ntg = 2 * j + ch;
        const int col = ntg * 16 + ln;
#pragma unroll
        for (int r = 0; r < 4; ++r) {
            int rg = row0 + kg * 4 + r;
            int b = rg >> 11, s = rg & 2047;
            size_t rowoff = ((size_t)b * SEQ + s) * 64;
            float val = acc[j][r];
            if (col < 64) {
                ushort h = f2bf(val);
                q_hi[rowoff + col] = h;
                q_lo[rowoff + col] = f2bf_trunc(val - bf2f(h));
            } else if (col < 128) {
                ushort h = f2bf(val);
                k_hi[rowoff + (col - 64)] = h;
                k_lo[rowoff + (col - 64)] = f2bf_trunc(val - bf2f(h));
            } else {
                v_t[((size_t)b * 64 + (col - 128)) * SEQ + s] = f2bf(val);
            }
        }
    }
}

// ---------------------------------------------------------------------------
// Kernel 2: causal flash attention, barrier-free.
// Wave = one 16-row q-tile, fully independent (no __syncthreads anywhere).
// Swapped QK^T: sacc = K . Q^T, so lane ln owns query-column ln ->
// softmax reduce = 16 lane-local regs + 2 shfl_xor (over kg lanes).
// K/V fragments read directly from global (L2-resident; batch pinned to XCD
// via b = blockIdx & 7).  P staged through tiny per-wave LDS (in-order DS).
// Block = 128 thr = 2 waves with balanced q-tiles (pid, 127-pid) -> 33
// k-tiles per block.  Grid = 8 batches x 64 = 512 blocks.
// ---------------------------------------------------------------------------
__global__ __launch_bounds__(128)
void attn_kernel(const ushort* __restrict__ q_hi, const ushort* __restrict__ q_lo,
                 const ushort* __restrict__ k_hi, const ushort* __restrict__ k_lo,
                 const ushort* __restrict__ v_t, float* __restrict__ out)
{
    __shared__ __align__(16) ushort pT[2][16][72];

    const int t    = threadIdx.x;
    const int lane = t & 63;
    const int wid  = t >> 6;          // 0,1
    const int ln   = lane & 15;
    const int kg   = lane >> 4;       // 0..3
    const int b    = blockIdx.x & 7;  // batch pinned to XCD
    const int pid  = blockIdx.x >> 3; // 0..63
    const int qt   = wid ? (127 - pid) : pid;   // 16-row q-tile, 0..127
    const int r0   = qt * 16;

    const ushort* qhb = q_hi + (size_t)b * SEQ * 64;
    const ushort* qlb = q_lo + (size_t)b * SEQ * 64;
    const ushort* khb = k_hi + (size_t)b * SEQ * 64;
    const ushort* klb = k_lo + (size_t)b * SEQ * 64;
    const ushort* vtb = v_t + (size_t)b * 64 * SEQ;
    float*        ob  = out + (size_t)b * SEQ * 64;

    // Q fragments (hi/lo, 2 k-steps) in registers for the whole tile
    short8 qh[2], ql[2];
#pragma unroll
    for (int ks = 0; ks < 2; ++ks) {
        size_t off = (size_t)(r0 + ln) * 64 + ks * 32 + kg * 8;
        qh[ks] = *(const short8*)(qhb + off);
        ql[ks] = *(const short8*)(qlb + off);
    }

    const f32x4 vzero = {0.f, 0.f, 0.f, 0.f};
    f32x4 o[4];
#pragma unroll
    for (int i = 0; i < 4; ++i) o[i] = vzero;
    float m_run = -INFINITY, l_run = 0.f;
    const int qrow = r0 + ln;         // the query this lane's softmax owns

    const int nt = qt / 4 + 1;        // 64-key tiles needed (causal)
    for (int jt = 0; jt < nt; ++jt) {
        const int j0 = jt * 64;
        const size_t kbase = (size_t)j0 * 64;

        // ---- issue all global loads for this tile up front ----
        short8 kfh[4][2], kfl[4][2], vf[4][2];
#pragma unroll
        for (int ct = 0; ct < 4; ++ct) {
            size_t off = kbase + (size_t)(ct * 16 + ln) * 64 + kg * 8;
            kfh[ct][0] = *(const short8*)(khb + off);
            kfh[ct][1] = *(const short8*)(khb + off + 32);
            kfl[ct][0] = *(const short8*)(klb + off);
            kfl[ct][1] = *(const short8*)(klb + off + 32);
        }
#pragma unroll
        for (int ht = 0; ht < 4; ++ht) {
            size_t voff = (size_t)(ht * 16 + ln) * SEQ + j0 + kg * 8;
            vf[ht][0] = *(const short8*)(vtb + voff);
            vf[ht][1] = *(const short8*)(vtb + voff + 32);
        }

        // ---- QK^T (swapped): sacc[ct][r] = score[key=j0+ct*16+kg*4+r][q=ln]
        f32x4 sacc[4];
#pragma unroll
        for (int ct = 0; ct < 4; ++ct) sacc[ct] = vzero;
#pragma unroll
        for (int ct = 0; ct < 4; ++ct) {
#pragma unroll
            for (int ks = 0; ks < 2; ++ks) {
                sacc[ct] = __builtin_amdgcn_mfma_f32_16x16x32_bf16(kfh[ct][ks], qh[ks], sacc[ct], 0, 0, 0);
                sacc[ct] = __builtin_amdgcn_mfma_f32_16x16x32_bf16(kfh[ct][ks], ql[ks], sacc[ct], 0, 0, 0);
                sacc[ct] = __builtin_amdgcn_mfma_f32_16x16x32_bf16(kfl[ct][ks], qh[ks], sacc[ct], 0, 0, 0);
            }
        }

        // ---- causal mask (diagonal tile only) ----
        if (jt == nt - 1) {
#pragma unroll
            for (int ct = 0; ct < 4; ++ct) {
                int kb0 = j0 + ct * 16 + kg * 4;
#pragma unroll
                for (int r = 0; r < 4; ++r)
                    if (kb0 + r > qrow) sacc[ct][r] = -1e30f;
            }
        }

        // ---- online softmax for query ln (16 local + 2 shfl) ----
        float mt_ = fmaxf(fmaxf(fmaxf(sacc[0][0], sacc[0][1]), fmaxf(sacc[0][2], sacc[0][3])),
                          fmaxf(fmaxf(sacc[1][0], sacc[1][1]), fmaxf(sacc[1][2], sacc[1][3])));
        float mt2 = fmaxf(fmaxf(fmaxf(sacc[2][0], sacc[2][1]), fmaxf(sacc[2][2], sacc[2][3])),
                          fmaxf(fmaxf(sacc[3][0], sacc[3][1]), fmaxf(sacc[3][2], sacc[3][3])));
        mt_ = fmaxf(mt_, mt2);
        mt_ = fmaxf(mt_, __shfl_xor(mt_, 16));
        mt_ = fmaxf(mt_, __shfl_xor(mt_, 32));
        float mn   = fmaxf(m_run, mt_);
        float corr = __expf(m_run - mn);     // 0 on first tile
        float p[4][4];
        float lt = 0.f;
#pragma unroll
        for (int ct = 0; ct < 4; ++ct)
#pragma unroll
            for (int r = 0; r < 4; ++r) {
                p[ct][r] = __expf(sacc[ct][r] - mn);
                lt += p[ct][r];
            }
        lt += __shfl_xor(lt, 16);
        lt += __shfl_xor(lt, 32);
        m_run = mn;
        l_run = l_run * corr + lt;

        // ---- P -> per-wave LDS (bf16, packed u32 stores) ----
#pragma unroll
        for (int ct = 0; ct < 4; ++ct) {
            uint u0 = (uint)f2bf(p[ct][0]) | ((uint)f2bf(p[ct][1]) << 16);
            uint u1 = (uint)f2bf(p[ct][2]) | ((uint)f2bf(p[ct][3]) << 16);
            *(uint*)&pT[wid][ln][ct * 16 + kg * 4]     = u0;
            *(uint*)&pT[wid][ln][ct * 16 + kg * 4 + 2] = u1;
        }

        // ---- rescale O (rows are q = kg*4+r -> broadcast corr) ----
        float corrq[4];
#pragma unroll
        for (int r = 0; r < 4; ++r) corrq[r] = __shfl(corr, kg * 4 + r);
#pragma unroll
        for (int ht = 0; ht < 4; ++ht)
#pragma unroll
            for (int r = 0; r < 4; ++r) o[ht][r] *= corrq[r];

        // ---- PV: o[q][h] += P[q][key] * V[key][h] ----
#pragma unroll
        for (int ks = 0; ks < 2; ++ks) {
            short8 pa = *(const short8*)&pT[wid][ln][ks * 32 + kg * 8];
#pragma unroll
            for (int ht = 0; ht < 4; ++ht)
                o[ht] = __builtin_amdgcn_mfma_f32_16x16x32_bf16(pa, vf[ht][ks], o[ht], 0, 0, 0);
        }
    }

    // ---- epilogue: divide by l (broadcast per output row), store ----
    float linv[4];
#pragma unroll
    for (int r = 0; r < 4; ++r) linv[r] = 1.0f / __shfl(l_run, kg * 4 + r);
#pragma unroll
    for (int ht = 0; ht < 4; ++ht)
#pragma unroll
        for (int r = 0; r < 4; ++r)
            ob[(size_t)(r0 + kg * 4 + r) * 64 + ht * 16 + ln] = o[ht][r] * linv[r];
}

// ---------------------------------------------------------------------------
extern "C" void kernel_launch(void* const* d_in, const int* in_sizes, int n_in,
                              void* d_out, int out_size, void* d_ws, size_t ws_size,
                              hipStream_t stream)
{
    const float* x  = (const float*)d_in[0];
    const float* Wq = (const float*)d_in[1];
    const float* Wk = (const float*)d_in[2];
    const float* Wv = (const float*)d_in[3];
    float* out = (float*)d_out;

    ushort* ws = (ushort*)d_ws;
    ushort* w_hi = ws + WHI_OFF;
    ushort* w_lo = ws + WLO_OFF;
    ushort* q_hi = ws + QHI_OFF;
    ushort* q_lo = ws + QLO_OFF;
    ushort* k_hi = ws + KHI_OFF;
    ushort* k_lo = ws + KLO_OFF;
    ushort* v_t  = ws + VT_OFF;

    split_w_kernel<<<dim3(576), dim3(256), 0, stream>>>(Wq, Wk, Wv, w_hi, w_lo);
    proj_kernel<<<dim3(512), dim3(256), 0, stream>>>(x, w_hi, w_lo,
                                                     q_hi, q_lo, k_hi, k_lo, v_t);
    attn_kernel<<<dim3(512), dim3(128), 0, stream>>>(q_hi, q_lo, k_hi, k_lo, v_t, out);
}

// Round 4
// 90.751 us; speedup vs baseline: 1.4438x; 1.4438x over previous
//
#include <hip/hip_runtime.h>
#include <math.h>

#define EMBED 768
#define SEQ   2048
#define NB    8
#define SQRT_E 27.712812921102035f   // sqrt(768), folded into Wq at split time

typedef short  short8 __attribute__((ext_vector_type(8)));
typedef float  f32x4  __attribute__((ext_vector_type(4)));

// ws layout (ushort element offsets)
#define WHI_OFF  0u
#define WLO_OFF  147456u
#define QHI_OFF  294912u
#define QLO_OFF  (294912u + 1u*1048576u)
#define KHI_OFF  (294912u + 2u*1048576u)
#define KLO_OFF  (294912u + 3u*1048576u)
#define VT_OFF   (294912u + 4u*1048576u)

__device__ __forceinline__ ushort f2bf(float f) {          // round-to-nearest
    unsigned u = __float_as_uint(f);
    return (ushort)((u + 0x7FFFu + ((u >> 16) & 1u)) >> 16);
}
__device__ __forceinline__ ushort f2bf_trunc(float f) {    // cheap, for lo part
    return (ushort)(__float_as_uint(f) >> 16);
}
__device__ __forceinline__ float bf2f(ushort h) {
    return __uint_as_float(((unsigned)h) << 16);
}

// ---------------------------------------------------------------------------
// Kernel 0: split W into bf16 hi/lo.  rows: [0,64)=Wq*sqrt(E), [64,128)=Wk,
// [128,192)=Wv.  w_hi/w_lo are [192][768] bf16 row-major.
// ---------------------------------------------------------------------------
__global__ __launch_bounds__(256)
void split_w_kernel(const float* __restrict__ Wq, const float* __restrict__ Wk,
                    const float* __restrict__ Wv,
                    ushort* __restrict__ w_hi, ushort* __restrict__ w_lo)
{
    int idx = blockIdx.x * 256 + threadIdx.x;
    if (idx >= 192 * EMBED) return;
    int row = idx / EMBED, e = idx - row * EMBED;
    float f;
    if (row < 64)       f = Wq[row * EMBED + e] * SQRT_E;
    else if (row < 128) f = Wk[(row - 64) * EMBED + e];
    else                f = Wv[(row - 128) * EMBED + e];
    ushort hi = f2bf(f);
    w_hi[idx] = hi;
    w_lo[idx] = f2bf_trunc(f - bf2f(hi));
}

// ---------------------------------------------------------------------------
// Kernel 1: QKV projection, LDS-staged with cross-barrier register prefetch.
// Block 256 thr = 4 waves (wm in {0,1} x ch in {0,1}); tile M=64 x N=192,
// K-chunk 64 (12 chunks).  Wave = 32 rows x 96 cols (2 m-tiles x 6 n-tiles,
// interleaved ntg = 2j+ch so every wave gets 4 qk-tiles + 2 v-tiles).
// Chunk c+1's global loads are issued right after the staging barrier of
// chunk c, overlapping the whole compute phase.  W-lo staged only for the
// 128 q/k rows (v needs no lo).  Grid 256 = 1 block/CU.
// ---------------------------------------------------------------------------
__global__ __launch_bounds__(256)
void proj_kernel(const float* __restrict__ x,
                 const ushort* __restrict__ w_hi, const ushort* __restrict__ w_lo,
                 ushort* __restrict__ q_hi, ushort* __restrict__ q_lo,
                 ushort* __restrict__ k_hi, ushort* __restrict__ k_lo,
                 ushort* __restrict__ v_t)
{
    __shared__ __align__(16) ushort xa_hi[64][72], xa_lo[64][72];
    __shared__ __align__(16) ushort wb_hi[192][72];
    __shared__ __align__(16) ushort wb_lo[128][72];

    const int t    = threadIdx.x;
    const int lane = t & 63;
    const int wid  = t >> 6;
    const int wm   = wid >> 1;      // 0,1: rows wm*32 .. +31
    const int ch   = wid & 1;       // col half (even/odd n-tiles)
    const int ln   = lane & 15;
    const int kg   = lane >> 4;     // 0..3
    const int row0 = blockIdx.x * 64;

    const int srow = t >> 2;            // 0..63 (staging row)
    const int skq  = (t & 3) * 16;      // staging col offset (elements)

    // prefetch registers
    float4 xr0, xr1, xr2, xr3;
    short8 wh0, wh1, wh2, wh3, wh4, wh5;
    short8 wl0, wl1, wl2, wl3;

#define LOAD_CHUNK(e0) do {                                                     \
        const float*  xp_ = x + (size_t)(row0 + srow) * EMBED + (e0) + skq;     \
        xr0 = *(const float4*)xp_;        xr1 = *(const float4*)(xp_ + 4);      \
        xr2 = *(const float4*)(xp_ + 8);  xr3 = *(const float4*)(xp_ + 12);     \
        const ushort* whp_ = w_hi + (size_t)srow * EMBED + (e0) + skq;          \
        wh0 = *(const short8*)whp_;                                             \
        wh1 = *(const short8*)(whp_ + 8);                                       \
        wh2 = *(const short8*)(whp_ + 64 * EMBED);                              \
        wh3 = *(const short8*)(whp_ + 64 * EMBED + 8);                          \
        wh4 = *(const short8*)(whp_ + 128 * EMBED);                             \
        wh5 = *(const short8*)(whp_ + 128 * EMBED + 8);                         \
        const ushort* wlp_ = w_lo + (size_t)srow * EMBED + (e0) + skq;          \
        wl0 = *(const short8*)wlp_;                                             \
        wl1 = *(const short8*)(wlp_ + 8);                                       \
        wl2 = *(const short8*)(wlp_ + 64 * EMBED);                              \
        wl3 = *(const short8*)(wlp_ + 64 * EMBED + 8);                          \
    } while (0)

    const f32x4 vzero = {0.f, 0.f, 0.f, 0.f};
    f32x4 acc[2][6];
#pragma unroll
    for (int mt = 0; mt < 2; ++mt)
#pragma unroll
        for (int j = 0; j < 6; ++j) acc[mt][j] = vzero;

    LOAD_CHUNK(0);

    for (int c = 0; c < 12; ++c) {
        if (c) __syncthreads();          // all waves done reading prev chunk
        // ---- stage regs -> LDS (x converted fp32 -> bf16 hi/lo) ----
        {
            const float fv[16] = {xr0.x, xr0.y, xr0.z, xr0.w,
                                  xr1.x, xr1.y, xr1.z, xr1.w,
                                  xr2.x, xr2.y, xr2.z, xr2.w,
                                  xr3.x, xr3.y, xr3.z, xr3.w};
            short8 h0, h1, l0, l1;
#pragma unroll
            for (int i = 0; i < 8; ++i) {
                ushort h = f2bf(fv[i]);
                h0[i] = (short)h;
                l0[i] = (short)f2bf_trunc(fv[i] - bf2f(h));
            }
#pragma unroll
            for (int i = 0; i < 8; ++i) {
                ushort h = f2bf(fv[8 + i]);
                h1[i] = (short)h;
                l1[i] = (short)f2bf_trunc(fv[8 + i] - bf2f(h));
            }
            *(short8*)&xa_hi[srow][skq]     = h0;
            *(short8*)&xa_hi[srow][skq + 8] = h1;
            *(short8*)&xa_lo[srow][skq]     = l0;
            *(short8*)&xa_lo[srow][skq + 8] = l1;
            *(short8*)&wb_hi[srow][skq]           = wh0;
            *(short8*)&wb_hi[srow][skq + 8]       = wh1;
            *(short8*)&wb_hi[srow + 64][skq]      = wh2;
            *(short8*)&wb_hi[srow + 64][skq + 8]  = wh3;
            *(short8*)&wb_hi[srow + 128][skq]     = wh4;
            *(short8*)&wb_hi[srow + 128][skq + 8] = wh5;
            *(short8*)&wb_lo[srow][skq]           = wl0;
            *(short8*)&wb_lo[srow][skq + 8]       = wl1;
            *(short8*)&wb_lo[srow + 64][skq]      = wl2;
            *(short8*)&wb_lo[srow + 64][skq + 8]  = wl3;
        }
        __syncthreads();
        // ---- prefetch next chunk (overlaps compute below) ----
        if (c < 11) LOAD_CHUNK((c + 1) * 64);

        // ---- fragments + MFMA ----
        short8 ah[2][2], al[2][2];
#pragma unroll
        for (int mt = 0; mt < 2; ++mt)
#pragma unroll
            for (int ks = 0; ks < 2; ++ks) {
                ah[mt][ks] = *(const short8*)&xa_hi[wm * 32 + mt * 16 + ln][ks * 32 + kg * 8];
                al[mt][ks] = *(const short8*)&xa_lo[wm * 32 + mt * 16 + ln][ks * 32 + kg * 8];
            }
#pragma unroll
        for (int j = 0; j < 6; ++j) {
            const int ntg = 2 * j + ch;
#pragma unroll
            for (int ks = 0; ks < 2; ++ks) {
                short8 bh = *(const short8*)&wb_hi[ntg * 16 + ln][ks * 32 + kg * 8];
#pragma unroll
                for (int mt = 0; mt < 2; ++mt)
                    acc[mt][j] = __builtin_amdgcn_mfma_f32_16x16x32_bf16(ah[mt][ks], bh, acc[mt][j], 0, 0, 0);
                if (j < 4) {   // qk tiles (ntg < 8): split correction terms
                    short8 bl = *(const short8*)&wb_lo[ntg * 16 + ln][ks * 32 + kg * 8];
#pragma unroll
                    for (int mt = 0; mt < 2; ++mt) {
                        acc[mt][j] = __builtin_amdgcn_mfma_f32_16x16x32_bf16(ah[mt][ks], bl, acc[mt][j], 0, 0, 0);
                        acc[mt][j] = __builtin_amdgcn_mfma_f32_16x16x32_bf16(al[mt][ks], bh, acc[mt][j], 0, 0, 0);
                    }
                }
            }
        }
    }
#undef LOAD_CHUNK

    // ---- epilogue: C layout col=lane&15, row=(lane>>4)*4+reg ----
#pragma unroll
    for (int mt = 0; mt < 2; ++mt) {
        const int rbase = row0 + wm * 32 + mt * 16 + kg * 4;
#pragma unroll
        for (int j = 0; j < 6; ++j) {
            const int ntg = 2 * j + ch;
            const int col = ntg * 16 + ln;
#pragma unroll
            for (int r = 0; r < 4; ++r) {
                int rg = rbase + r;
                int b = rg >> 11, s = rg & 2047;
                size_t rowoff = ((size_t)b * SEQ + s) * 64;
                float val = acc[mt][j][r];
                if (col < 64) {
                    ushort h = f2bf(val);
                    q_hi[rowoff + col] = h;
                    q_lo[rowoff + col] = f2bf_trunc(val - bf2f(h));
                } else if (col < 128) {
                    ushort h = f2bf(val);
                    k_hi[rowoff + (col - 64)] = h;
                    k_lo[rowoff + (col - 64)] = f2bf_trunc(val - bf2f(h));
                } else {
                    v_t[((size_t)b * 64 + (col - 128)) * SEQ + s] = f2bf(val);
                }
            }
        }
    }
}

// ---------------------------------------------------------------------------
// Kernel 2: causal flash attention, k-split 4.
// Block 256 thr = 4 waves, all on the SAME 16-row q-tile; wave w processes
// k-tiles jt = w, w+4, w+8, ... (interleaved quarters), merge via LDS at end
// (single barrier).  Swapped QK^T (lane owns query-column ln).  K/V read
// straight from global (L2-resident, batch pinned to XCD via bid&7).
// Grid = 8 x 128 = 1024 blocks, longest q-tiles first (qt = 127 - bid>>3).
// __launch_bounds__(256,4): cap 128 VGPR -> 16 waves/CU (4/SIMD).
// ---------------------------------------------------------------------------
__global__ __launch_bounds__(256, 4)
void attn_kernel(const ushort* __restrict__ q_hi, const ushort* __restrict__ q_lo,
                 const ushort* __restrict__ k_hi, const ushort* __restrict__ k_lo,
                 const ushort* __restrict__ v_t, float* __restrict__ out)
{
    __shared__ __align__(16) ushort pT[4][16][72];
    __shared__ float obuf[3][16][72];
    __shared__ float mbuf[3][16], lbuf[3][16];

    const int t    = threadIdx.x;
    const int lane = t & 63;
    const int w    = t >> 6;          // k-split quarter 0..3
    const int ln   = lane & 15;
    const int kg   = lane >> 4;       // 0..3
    const int b    = blockIdx.x & 7;  // batch pinned to XCD
    const int qt   = 127 - (blockIdx.x >> 3);   // longest first
    const int r0   = qt * 16;

    const ushort* qhb = q_hi + (size_t)b * SEQ * 64;
    const ushort* qlb = q_lo + (size_t)b * SEQ * 64;
    const ushort* khb = k_hi + (size_t)b * SEQ * 64;
    const ushort* klb = k_lo + (size_t)b * SEQ * 64;
    const ushort* vtb = v_t + (size_t)b * 64 * SEQ;
    float*        ob  = out + (size_t)b * SEQ * 64;

    // Q fragments (hi/lo, 2 k-steps) in registers for the whole tile
    short8 qh[2], ql[2];
#pragma unroll
    for (int ks = 0; ks < 2; ++ks) {
        size_t off = (size_t)(r0 + ln) * 64 + ks * 32 + kg * 8;
        qh[ks] = *(const short8*)(qhb + off);
        ql[ks] = *(const short8*)(qlb + off);
    }

    const f32x4 vzero = {0.f, 0.f, 0.f, 0.f};
    f32x4 o[4];
#pragma unroll
    for (int i = 0; i < 4; ++i) o[i] = vzero;
    float m_run = -INFINITY, l_run = 0.f;
    const int qrow = r0 + ln;
    const int nt = qt / 4 + 1;        // causal 64-key tiles for this q-tile

    for (int jt = w; jt < nt; jt += 4) {
        const int j0 = jt * 64;
        const size_t kbase = (size_t)j0 * 64;

        // ---- issue all global loads for this tile up front ----
        short8 kfh[4][2], kfl[4][2], vf[4][2];
#pragma unroll
        for (int ct = 0; ct < 4; ++ct) {
            size_t off = kbase + (size_t)(ct * 16 + ln) * 64 + kg * 8;
            kfh[ct][0] = *(const short8*)(khb + off);
            kfh[ct][1] = *(const short8*)(khb + off + 32);
            kfl[ct][0] = *(const short8*)(klb + off);
            kfl[ct][1] = *(const short8*)(klb + off + 32);
        }
#pragma unroll
        for (int ht = 0; ht < 4; ++ht) {
            size_t voff = (size_t)(ht * 16 + ln) * SEQ + j0 + kg * 8;
            vf[ht][0] = *(const short8*)(vtb + voff);
            vf[ht][1] = *(const short8*)(vtb + voff + 32);
        }

        // ---- QK^T (swapped): sacc[ct][r] = score[key=j0+ct*16+kg*4+r][q=ln]
        f32x4 sacc[4];
#pragma unroll
        for (int ct = 0; ct < 4; ++ct) sacc[ct] = vzero;
#pragma unroll
        for (int ct = 0; ct < 4; ++ct) {
#pragma unroll
            for (int ks = 0; ks < 2; ++ks) {
                sacc[ct] = __builtin_amdgcn_mfma_f32_16x16x32_bf16(kfh[ct][ks], qh[ks], sacc[ct], 0, 0, 0);
                sacc[ct] = __builtin_amdgcn_mfma_f32_16x16x32_bf16(kfh[ct][ks], ql[ks], sacc[ct], 0, 0, 0);
                sacc[ct] = __builtin_amdgcn_mfma_f32_16x16x32_bf16(kfl[ct][ks], qh[ks], sacc[ct], 0, 0, 0);
            }
        }

        // ---- causal mask (diagonal tile only) ----
        if (jt == nt - 1) {
#pragma unroll
            for (int ct = 0; ct < 4; ++ct) {
                int kb0 = j0 + ct * 16 + kg * 4;
#pragma unroll
                for (int r = 0; r < 4; ++r)
                    if (kb0 + r > qrow) sacc[ct][r] = -1e30f;
            }
        }

        // ---- online softmax for query ln (16 local + 2 shfl) ----
        float mt_ = fmaxf(fmaxf(fmaxf(sacc[0][0], sacc[0][1]), fmaxf(sacc[0][2], sacc[0][3])),
                          fmaxf(fmaxf(sacc[1][0], sacc[1][1]), fmaxf(sacc[1][2], sacc[1][3])));
        float mt2 = fmaxf(fmaxf(fmaxf(sacc[2][0], sacc[2][1]), fmaxf(sacc[2][2], sacc[2][3])),
                          fmaxf(fmaxf(sacc[3][0], sacc[3][1]), fmaxf(sacc[3][2], sacc[3][3])));
        mt_ = fmaxf(mt_, mt2);
        mt_ = fmaxf(mt_, __shfl_xor(mt_, 16));
        mt_ = fmaxf(mt_, __shfl_xor(mt_, 32));
        float mn   = fmaxf(m_run, mt_);
        float corr = __expf(m_run - mn);     // 0 on first tile
        float p[4][4];
        float lt = 0.f;
#pragma unroll
        for (int ct = 0; ct < 4; ++ct)
#pragma unroll
            for (int r = 0; r < 4; ++r) {
                p[ct][r] = __expf(sacc[ct][r] - mn);
                lt += p[ct][r];
            }
        lt += __shfl_xor(lt, 16);
        lt += __shfl_xor(lt, 32);
        m_run = mn;
        l_run = l_run * corr + lt;

        // ---- P -> per-wave LDS (bf16, packed u32 stores) ----
#pragma unroll
        for (int ct = 0; ct < 4; ++ct) {
            uint u0 = (uint)f2bf(p[ct][0]) | ((uint)f2bf(p[ct][1]) << 16);
            uint u1 = (uint)f2bf(p[ct][2]) | ((uint)f2bf(p[ct][3]) << 16);
            *(uint*)&pT[w][ln][ct * 16 + kg * 4]     = u0;
            *(uint*)&pT[w][ln][ct * 16 + kg * 4 + 2] = u1;
        }

        // ---- rescale O (rows are q = kg*4+r -> broadcast corr) ----
        float corrq[4];
#pragma unroll
        for (int r = 0; r < 4; ++r) corrq[r] = __shfl(corr, kg * 4 + r);
#pragma unroll
        for (int ht = 0; ht < 4; ++ht)
#pragma unroll
            for (int r = 0; r < 4; ++r) o[ht][r] *= corrq[r];

        // ---- PV: o[q][h] += P[q][key] * V[key][h] ----
#pragma unroll
        for (int ks = 0; ks < 2; ++ks) {
            short8 pa = *(const short8*)&pT[w][ln][ks * 32 + kg * 8];
#pragma unroll
            for (int ht = 0; ht < 4; ++ht)
                o[ht] = __builtin_amdgcn_mfma_f32_16x16x32_bf16(pa, vf[ht][ks], o[ht], 0, 0, 0);
        }
    }

    // ---- merge the 4 k-split partials ----
    if (w > 0) {
#pragma unroll
        for (int ht = 0; ht < 4; ++ht)
#pragma unroll
            for (int r = 0; r < 4; ++r)
                obuf[w - 1][kg * 4 + r][ht * 16 + ln] = o[ht][r];
        if (kg == 0) { mbuf[w - 1][ln] = m_run; lbuf[w - 1][ln] = l_run; }
    }
    __syncthreads();
    if (w == 0) {
        float m1 = mbuf[0][ln], m2 = mbuf[1][ln], m3 = mbuf[2][ln];
        float mm = fmaxf(fmaxf(m_run, m1), fmaxf(m2, m3));
        float c0 = __expf(m_run - mm);
        float c1 = __expf(m1 - mm);
        float c2 = __expf(m2 - mm);
        float c3 = __expf(m3 - mm);
        float li = l_run * c0 + lbuf[0][ln] * c1 + lbuf[1][ln] * c2 + lbuf[2][ln] * c3;
        float inv = 1.0f / li;
        float c0q[4], c1q[4], c2q[4], c3q[4], ivq[4];
#pragma unroll
        for (int r = 0; r < 4; ++r) {
            int src = kg * 4 + r;
            c0q[r] = __shfl(c0, src);
            c1q[r] = __shfl(c1, src);
            c2q[r] = __shfl(c2, src);
            c3q[r] = __shfl(c3, src);
            ivq[r] = __shfl(inv, src);
        }
#pragma unroll
        for (int ht = 0; ht < 4; ++ht)
#pragma unroll
            for (int r = 0; r < 4; ++r) {
                float val = o[ht][r] * c0q[r]
                          + obuf[0][kg * 4 + r][ht * 16 + ln] * c1q[r]
                          + obuf[1][kg * 4 + r][ht * 16 + ln] * c2q[r]
                          + obuf[2][kg * 4 + r][ht * 16 + ln] * c3q[r];
                ob[(size_t)(r0 + kg * 4 + r) * 64 + ht * 16 + ln] = val * ivq[r];
            }
    }
}

// ---------------------------------------------------------------------------
extern "C" void kernel_launch(void* const* d_in, const int* in_sizes, int n_in,
                              void* d_out, int out_size, void* d_ws, size_t ws_size,
                              hipStream_t stream)
{
    const float* x  = (const float*)d_in[0];
    const float* Wq = (const float*)d_in[1];
    const float* Wk = (const float*)d_in[2];
    const float* Wv = (const float*)d_in[3];
    float* out = (float*)d_out;

    ushort* ws = (ushort*)d_ws;
    ushort* w_hi = ws + WHI_OFF;
    ushort* w_lo = ws + WLO_OFF;
    ushort* q_hi = ws + QHI_OFF;
    ushort* q_lo = ws + QLO_OFF;
    ushort* k_hi = ws + KHI_OFF;
    ushort* k_lo = ws + KLO_OFF;
    ushort* v_t  = ws + VT_OFF;

    split_w_kernel<<<dim3(576), dim3(256), 0, stream>>>(Wq, Wk, Wv, w_hi, w_lo);
    proj_kernel<<<dim3(256), dim3(256), 0, stream>>>(x, w_hi, w_lo,
                                                     q_hi, q_lo, k_hi, k_lo, v_t);
    attn_kernel<<<dim3(1024), dim3(256), 0, stream>>>(q_hi, q_lo, k_hi, k_lo, v_t, out);
}